// Round 7
// baseline (19.960 us; speedup 1.0000x reference)
//
#include <hip/hip_runtime.h>

#define CHUNK 6
#define BLK 256

// Stage 1: gru is LDS-staged (coalesced float4 global loads, register-staged
// to overlap the resnet/y stream, then contiguous 96B chunk-quad reads from
// LDS). resnet/y/avg: perfectly coalesced float4. One partial triple per
// block -> d_ws (SoA). No atomics.
__global__ __launch_bounds__(BLK) void loss_partial_kernel(
    const float* __restrict__ resnet, const float* __restrict__ gru,
    const float* __restrict__ avgp,   const float* __restrict__ y,
    const float* __restrict__ avgh,
    float* __restrict__ partials, int nb, int C, int M, int N)
{
    const int tid = threadIdx.x;
    const int gid = blockIdx.x * BLK + tid;
    const int T   = nb * BLK;

    float s_l1a = 0.f, s_l1b = 0.f, s_sm = 0.f;

    // ---- gru: issue coalesced loads into registers FIRST (T14 issue-early)
    const int Cq    = C >> 2;                    // chunk quads (4 chunks = 6 f4)
    const int qbase = blockIdx.x * BLK;          // this block's first quad
    int nq = Cq - qbase;                         // quads this block owns
    nq = (nq < 0) ? 0 : ((nq > BLK) ? BLK : nq);
    const int nf4 = 6 * nq;                      // float4s to stage
    const float4* gsrc = reinterpret_cast<const float4*>(gru) + 6 * qbase;
    float4 gv[6];
    #pragma unroll
    for (int k = 0; k < 6; ++k) {
        int j = tid + BLK * k;
        if (j < nf4) gv[k] = gsrc[j];            // lane-contiguous: perfect
    }

    // ---- avg: one coalesced float4 per thread
    const int Mv4 = M >> 2;
    if (gid < Mv4) {
        float4 p = reinterpret_cast<const float4*>(avgp)[gid];
        float4 h = reinterpret_cast<const float4*>(avgh)[gid];
        s_l1b = fabsf(p.x - h.x) + fabsf(p.y - h.y)
              + fabsf(p.z - h.z) + fabsf(p.w - h.w);
    }

    // ---- resnet vs y: coalesced float4 grid-stride (~6 iters)
    const int Nv4 = N >> 2;
    const float4* r4 = reinterpret_cast<const float4*>(resnet);
    const float4* y4 = reinterpret_cast<const float4*>(y);
    for (int i = gid; i < Nv4; i += T) {
        float4 r = r4[i], v = y4[i];
        s_l1a += fabsf(r.x - v.x) + fabsf(r.y - v.y)
               + fabsf(r.z - v.z) + fabsf(r.w - v.w);
    }

    // ---- scalar tails (empty at this problem's sizes)
    if (gid == 0) {
        for (int k = Nv4 << 2; k < N; ++k) s_l1a += fabsf(resnet[k] - y[k]);
        for (int k = Mv4 << 2; k < M; ++k) s_l1b += fabsf(avgp[k] - avgh[k]);
        for (int c = Cq << 2; c < C; ++c) {
            int base = CHUNK * c;
            float x0=gru[base],x1=gru[base+1],x2=gru[base+2];
            float x3=gru[base+3],x4=gru[base+4],x5=gru[base+5];
            float m = (x0+x1+x2+x3+x4+x5) * (1.0f/6.0f);
            s_sm += fabsf(x0-m)+fabsf(x1-m)+fabsf(x2-m)
                  + fabsf(x3-m)+fabsf(x4-m)+fabsf(x5-m);
        }
    }

    // ---- T14 write-late: park staged gru in LDS, then read own quad
    __shared__ float4 lds4[BLK * 6];             // 24 KiB
    #pragma unroll
    for (int k = 0; k < 6; ++k) {
        int j = tid + BLK * k;
        if (j < nf4) lds4[j] = gv[k];
    }
    __syncthreads();

    if (tid < nq) {
        float4 q0 = lds4[6*tid+0], q1 = lds4[6*tid+1], q2 = lds4[6*tid+2];
        float4 q3 = lds4[6*tid+3], q4 = lds4[6*tid+4], q5 = lds4[6*tid+5];
        float m0 = (q0.x + q0.y + q0.z + q0.w + q1.x + q1.y) * (1.0f / 6.0f);
        float m1 = (q1.z + q1.w + q2.x + q2.y + q2.z + q2.w) * (1.0f / 6.0f);
        float m2 = (q3.x + q3.y + q3.z + q3.w + q4.x + q4.y) * (1.0f / 6.0f);
        float m3 = (q4.z + q4.w + q5.x + q5.y + q5.z + q5.w) * (1.0f / 6.0f);
        s_sm += fabsf(q0.x-m0)+fabsf(q0.y-m0)+fabsf(q0.z-m0)+fabsf(q0.w-m0)
              + fabsf(q1.x-m0)+fabsf(q1.y-m0)
              + fabsf(q1.z-m1)+fabsf(q1.w-m1)
              + fabsf(q2.x-m1)+fabsf(q2.y-m1)+fabsf(q2.z-m1)+fabsf(q2.w-m1)
              + fabsf(q3.x-m2)+fabsf(q3.y-m2)+fabsf(q3.z-m2)+fabsf(q3.w-m2)
              + fabsf(q4.x-m2)+fabsf(q4.y-m2)
              + fabsf(q4.z-m3)+fabsf(q4.w-m3)
              + fabsf(q5.x-m3)+fabsf(q5.y-m3)+fabsf(q5.z-m3)+fabsf(q5.w-m3);
    }

    // ---- block reduction: wave shuffle + 4-wave LDS
    #pragma unroll
    for (int off = 32; off > 0; off >>= 1) {
        s_l1a += __shfl_down(s_l1a, off, 64);
        s_l1b += __shfl_down(s_l1b, off, 64);
        s_sm  += __shfl_down(s_sm,  off, 64);
    }
    __shared__ float red0[4], red1[4], red2[4];
    int wave = tid >> 6, lane = tid & 63;
    if (lane == 0) { red0[wave] = s_l1a; red1[wave] = s_l1b; red2[wave] = s_sm; }
    __syncthreads();

    if (tid == 0) {
        partials[blockIdx.x]          = red0[0] + red0[1] + red0[2] + red0[3];
        partials[nb + blockIdx.x]     = red1[0] + red1[1] + red1[2] + red1[3];
        partials[2 * nb + blockIdx.x] = red2[0] + red2[1] + red2[2] + red2[3];
    }
}

// Stage 2: one 512-thread block (single load round over ~489 partials),
// double accumulate + finalize.
__global__ __launch_bounds__(512) void loss_reduce_kernel(
    const float* __restrict__ partials, int nb,
    float* __restrict__ out, int N, int M)
{
    double a = 0.0, b = 0.0, c = 0.0;
    for (int i = threadIdx.x; i < nb; i += 512) {
        a += (double)partials[i];
        b += (double)partials[nb + i];
        c += (double)partials[2 * nb + i];
    }
    #pragma unroll
    for (int off = 32; off > 0; off >>= 1) {
        a += __shfl_down(a, off, 64);
        b += __shfl_down(b, off, 64);
        c += __shfl_down(c, off, 64);
    }
    __shared__ double ra[8], rb[8], rc[8];
    int wave = threadIdx.x >> 6, lane = threadIdx.x & 63;
    if (lane == 0) { ra[wave] = a; rb[wave] = b; rc[wave] = c; }
    __syncthreads();

    if (threadIdx.x == 0) {
        double sa = 0.0, sb = 0.0, sc = 0.0;
        #pragma unroll
        for (int w = 0; w < 8; ++w) { sa += ra[w]; sb += rb[w]; sc += rc[w]; }
        double l1     = sa / (double)N + sb / (double)M;
        double smooth = sc / (double)CHUNK;
        double total  = l1 + 100.0 * smooth;
        out[0] = (float)total;
        out[1] = (float)l1;
        out[2] = (float)smooth;
    }
}

extern "C" void kernel_launch(void* const* d_in, const int* in_sizes, int n_in,
                              void* d_out, int out_size, void* d_ws, size_t ws_size,
                              hipStream_t stream) {
    const float* resnet = (const float*)d_in[0];
    const float* gru    = (const float*)d_in[1];
    const float* avgp   = (const float*)d_in[2];
    const float* y      = (const float*)d_in[3];
    const float* avgh   = (const float*)d_in[4];
    float* out = (float*)d_out;

    int N = in_sizes[0];          // 3,000,000
    int M = in_sizes[2];          // 500,000
    int C = N / CHUNK;            // 500,000 chunks

    int Cq  = C >> 2;             // 125,000 quads
    int Mv4 = M >> 2;             // 125,000 float4s
    int work = (Cq > Mv4) ? Cq : Mv4;
    if (work < 1) work = 1;
    int nb = (work + BLK - 1) / BLK;          // 489 blocks

    float* partials = (float*)d_ws;           // 3 * nb floats

    loss_partial_kernel<<<nb, BLK, 0, stream>>>(resnet, gru, avgp, y, avgh,
                                                partials, nb, C, M, N);
    loss_reduce_kernel<<<1, 512, 0, stream>>>(partials, nb, out, N, M);
}

// Round 8
// 15.349 us; speedup vs baseline: 1.3004x; 1.3004x over previous
//
#include <hip/hip_runtime.h>

#define CHUNK 6
#define BLK 256

// Stage 1:
//  - resnet/y/avg: perfectly coalesced float4 streams (as R6).
//  - gru: 3-lane shuffle scheme. Lane l (<63) of each wave loads float4
//    idx = base + l (lane-contiguous). 3 consecutive f4s = 2 chunks, handled
//    by 3 consecutive lanes; chunk means assembled via 2 ds_bpermute shuffles.
//    No LDS, no strided loads, no registers held across phases.
// One partial triple per block -> d_ws (SoA). No atomics.
__global__ __launch_bounds__(BLK) void loss_partial_kernel(
    const float* __restrict__ resnet, const float* __restrict__ gru,
    const float* __restrict__ avgp,   const float* __restrict__ y,
    const float* __restrict__ avgh,
    float* __restrict__ partials, int nb, int C, int M, int N)
{
    const int tid  = threadIdx.x;
    const int gid  = blockIdx.x * BLK + tid;
    const int T    = nb * BLK;
    const int lane = tid & 63;
    const int wv0  = (blockIdx.x * (BLK >> 6)) + (tid >> 6);   // global wave id
    const int NW   = nb * (BLK >> 6);                          // total waves

    float s_l1a = 0.f, s_l1b = 0.f, s_sm = 0.f;

    // ---- avg: one coalesced float4 per thread (T >= Mv4 here)
    const int Mv4 = M >> 2;
    for (int i = gid; i < Mv4; i += T) {
        float4 p = reinterpret_cast<const float4*>(avgp)[i];
        float4 h = reinterpret_cast<const float4*>(avgh)[i];
        s_l1b += fabsf(p.x - h.x) + fabsf(p.y - h.y)
               + fabsf(p.z - h.z) + fabsf(p.w - h.w);
    }

    // ---- resnet vs y: coalesced float4 grid-stride (~6 iters)
    const int Nv4 = N >> 2;
    const float4* r4 = reinterpret_cast<const float4*>(resnet);
    const float4* y4 = reinterpret_cast<const float4*>(y);
    for (int i = gid; i < Nv4; i += T) {
        float4 r = r4[i], v = y4[i];
        s_l1a += fabsf(r.x - v.x) + fabsf(r.y - v.y)
               + fabsf(r.z - v.z) + fabsf(r.w - v.w);
    }

    // ---- gru smoothness: 3-lane shuffle groups, fully coalesced loads.
    // f4s used: G3 = 3*(C/2); since G3 % 3 == 0, groups are always whole.
    // base is a multiple of 63 (and of 3), so idx % 3 == lane % 3.
    {
        const int G3 = 3 * (C >> 1);
        const float4* g4 = reinterpret_cast<const float4*>(gru);
        const float inv6 = 1.0f / 6.0f;
        const int r = lane % 3;
        for (int base = wv0 * 63; base < G3; base += NW * 63) {
            const int idx = base + lane;
            float4 v = make_float4(0.f, 0.f, 0.f, 0.f);
            const bool act = (lane < 63) && (idx < G3);
            if (act) v = g4[idx];
            const float s   = v.x + v.y + v.z + v.w;
            const float hlo = v.x + v.y;
            const float hhi = v.z + v.w;
            // v1 pulled from lane-1: r==1 wants its s, r==2 wants its hhi
            // v2 pulled from lane+1: r==0 wants its hlo, r==1 wants its s
            const float v1 = (r == 0) ? s : hhi;
            const float v2 = (r == 1) ? hlo : s;
            const float recv1 = __shfl(v1, lane - 1, 64);
            const float recv2 = __shfl(v2, lane + 1, 64);
            if (act) {
                float mA = (r == 0) ? (s + recv2) * inv6
                         : (r == 1) ? (recv1 + hlo) * inv6
                                    : (recv1 + s) * inv6;
                float mB = (r == 1) ? (hhi + recv2) * inv6 : mA;
                s_sm += fabsf(v.x - mA) + fabsf(v.y - mA)
                      + fabsf(v.z - mB) + fabsf(v.w - mB);
            }
        }
    }

    // ---- scalar tails (empty at this problem's sizes)
    if (gid == 0) {
        for (int k = Nv4 << 2; k < N; ++k) s_l1a += fabsf(resnet[k] - y[k]);
        for (int k = Mv4 << 2; k < M; ++k) s_l1b += fabsf(avgp[k] - avgh[k]);
        if (C & 1) {   // leftover odd chunk not covered by pair-groups
            int base = CHUNK * (C - 1);
            float x0=gru[base],x1=gru[base+1],x2=gru[base+2];
            float x3=gru[base+3],x4=gru[base+4],x5=gru[base+5];
            float m = (x0+x1+x2+x3+x4+x5) * (1.0f/6.0f);
            s_sm += fabsf(x0-m)+fabsf(x1-m)+fabsf(x2-m)
                  + fabsf(x3-m)+fabsf(x4-m)+fabsf(x5-m);
        }
    }

    // ---- block reduction: wave shuffle + 4-wave LDS
    #pragma unroll
    for (int off = 32; off > 0; off >>= 1) {
        s_l1a += __shfl_down(s_l1a, off, 64);
        s_l1b += __shfl_down(s_l1b, off, 64);
        s_sm  += __shfl_down(s_sm,  off, 64);
    }
    __shared__ float red0[4], red1[4], red2[4];
    int wave = tid >> 6;
    if (lane == 0) { red0[wave] = s_l1a; red1[wave] = s_l1b; red2[wave] = s_sm; }
    __syncthreads();

    if (tid == 0) {
        partials[blockIdx.x]          = red0[0] + red0[1] + red0[2] + red0[3];
        partials[nb + blockIdx.x]     = red1[0] + red1[1] + red1[2] + red1[3];
        partials[2 * nb + blockIdx.x] = red2[0] + red2[1] + red2[2] + red2[3];
    }
}

// Stage 2: one 256-thread block reduces nb partial triples (double) + finalizes.
__global__ __launch_bounds__(256) void loss_reduce_kernel(
    const float* __restrict__ partials, int nb,
    float* __restrict__ out, int N, int M)
{
    double a = 0.0, b = 0.0, c = 0.0;
    for (int i = threadIdx.x; i < nb; i += 256) {
        a += (double)partials[i];
        b += (double)partials[nb + i];
        c += (double)partials[2 * nb + i];
    }
    #pragma unroll
    for (int off = 32; off > 0; off >>= 1) {
        a += __shfl_down(a, off, 64);
        b += __shfl_down(b, off, 64);
        c += __shfl_down(c, off, 64);
    }
    __shared__ double ra[4], rb[4], rc[4];
    int wave = threadIdx.x >> 6, lane = threadIdx.x & 63;
    if (lane == 0) { ra[wave] = a; rb[wave] = b; rc[wave] = c; }
    __syncthreads();

    if (threadIdx.x == 0) {
        double sa = ra[0] + ra[1] + ra[2] + ra[3];
        double sb = rb[0] + rb[1] + rb[2] + rb[3];
        double sc = rc[0] + rc[1] + rc[2] + rc[3];
        double l1     = sa / (double)N + sb / (double)M;
        double smooth = sc / (double)CHUNK;
        double total  = l1 + 100.0 * smooth;
        out[0] = (float)total;
        out[1] = (float)l1;
        out[2] = (float)smooth;
    }
}

extern "C" void kernel_launch(void* const* d_in, const int* in_sizes, int n_in,
                              void* d_out, int out_size, void* d_ws, size_t ws_size,
                              hipStream_t stream) {
    const float* resnet = (const float*)d_in[0];
    const float* gru    = (const float*)d_in[1];
    const float* avgp   = (const float*)d_in[2];
    const float* y      = (const float*)d_in[3];
    const float* avgh   = (const float*)d_in[4];
    float* out = (float*)d_out;

    int N = in_sizes[0];          // 3,000,000
    int M = in_sizes[2];          // 500,000
    int C = N / CHUNK;            // 500,000 chunks

    int Cq  = C >> 2;             // 125,000 (kept for identical grid to R6)
    int Mv4 = M >> 2;             // 125,000
    int work = (Cq > Mv4) ? Cq : Mv4;
    if (work < 1) work = 1;
    int nb = (work + BLK - 1) / BLK;          // 489 blocks

    float* partials = (float*)d_ws;           // 3 * nb floats

    loss_partial_kernel<<<nb, BLK, 0, stream>>>(resnet, gru, avgp, y, avgh,
                                                partials, nb, C, M, N);
    loss_reduce_kernel<<<1, 256, 0, stream>>>(partials, nb, out, N, M);
}

// Round 9
// 13.423 us; speedup vs baseline: 1.4870x; 1.1435x over previous
//
#include <hip/hip_runtime.h>

#define CHUNK 6
#define BLK 256

// Stage 1: chunk-QUAD per thread. gru: 6 consecutive float4s (96B, 4 chunks).
// resnet/y/avg: fully coalesced float4 grid-stride (no chunk structure needed).
// One partial triple per block -> d_ws (SoA). No atomics anywhere.
// NOTE (R7/R8 evidence): do NOT "fix" the 96B-stride gru loads — LDS staging
// (+6.2us) and 3-lane shuffle regroup (+1.6us) both regressed; L1 absorbs the
// TA amplification and this latency-tight kernel tolerates no extra
// critical-path work.
__global__ __launch_bounds__(BLK) void loss_partial_kernel(
    const float* __restrict__ resnet, const float* __restrict__ gru,
    const float* __restrict__ avgp,   const float* __restrict__ y,
    const float* __restrict__ avgh,
    float* __restrict__ partials, int nb, int C, int M, int N)
{
    const int tid = threadIdx.x;
    const int gid = blockIdx.x * BLK + tid;
    const int T   = nb * BLK;

    float s_l1a = 0.f, s_l1b = 0.f, s_sm = 0.f;

    // ---- gru quad: issue all 6 loads up front (MLP), compute later
    const int Cq = C >> 2;                       // chunk quads
    const float4* g4 = reinterpret_cast<const float4*>(gru);
    float4 q0, q1, q2, q3, q4, q5;
    const bool have_q = (gid < Cq);
    if (have_q) {
        const float4* p = g4 + 6 * gid;
        q0 = p[0]; q1 = p[1]; q2 = p[2]; q3 = p[3]; q4 = p[4]; q5 = p[5];
    }

    // ---- avg: one coalesced float4 (Mv4 == thread count here)
    const int Mv4 = M >> 2;
    if (gid < Mv4) {
        float4 p = reinterpret_cast<const float4*>(avgp)[gid];
        float4 h = reinterpret_cast<const float4*>(avgh)[gid];
        s_l1b = fabsf(p.x - h.x) + fabsf(p.y - h.y)
              + fabsf(p.z - h.z) + fabsf(p.w - h.w);
    }

    // ---- resnet vs y: coalesced float4 grid-stride (~6 iters)
    const int Nv4 = N >> 2;
    const float4* r4 = reinterpret_cast<const float4*>(resnet);
    const float4* y4 = reinterpret_cast<const float4*>(y);
    for (int i = gid; i < Nv4; i += T) {
        float4 r = r4[i], v = y4[i];
        s_l1a += fabsf(r.x - v.x) + fabsf(r.y - v.y)
               + fabsf(r.z - v.z) + fabsf(r.w - v.w);
    }

    // ---- gru smoothness compute (loads long since landed)
    if (have_q) {
        // chunk0 = q0.xyzw q1.xy | chunk1 = q1.zw q2.xyzw
        // chunk2 = q3.xyzw q4.xy | chunk3 = q4.zw q5.xyzw
        float m0 = (q0.x + q0.y + q0.z + q0.w + q1.x + q1.y) * (1.0f / 6.0f);
        float m1 = (q1.z + q1.w + q2.x + q2.y + q2.z + q2.w) * (1.0f / 6.0f);
        float m2 = (q3.x + q3.y + q3.z + q3.w + q4.x + q4.y) * (1.0f / 6.0f);
        float m3 = (q4.z + q4.w + q5.x + q5.y + q5.z + q5.w) * (1.0f / 6.0f);
        s_sm = fabsf(q0.x-m0)+fabsf(q0.y-m0)+fabsf(q0.z-m0)+fabsf(q0.w-m0)
             + fabsf(q1.x-m0)+fabsf(q1.y-m0)
             + fabsf(q1.z-m1)+fabsf(q1.w-m1)
             + fabsf(q2.x-m1)+fabsf(q2.y-m1)+fabsf(q2.z-m1)+fabsf(q2.w-m1)
             + fabsf(q3.x-m2)+fabsf(q3.y-m2)+fabsf(q3.z-m2)+fabsf(q3.w-m2)
             + fabsf(q4.x-m2)+fabsf(q4.y-m2)
             + fabsf(q4.z-m3)+fabsf(q4.w-m3)
             + fabsf(q5.x-m3)+fabsf(q5.y-m3)+fabsf(q5.z-m3)+fabsf(q5.w-m3);
    }

    // ---- scalar tails (empty at this problem's sizes)
    if (gid == 0) {
        for (int k = Nv4 << 2; k < N; ++k) s_l1a += fabsf(resnet[k] - y[k]);
        for (int k = Mv4 << 2; k < M; ++k) s_l1b += fabsf(avgp[k] - avgh[k]);
        for (int c = Cq << 2; c < C; ++c) {
            int base = CHUNK * c;
            float x0=gru[base],x1=gru[base+1],x2=gru[base+2];
            float x3=gru[base+3],x4=gru[base+4],x5=gru[base+5];
            float m = (x0+x1+x2+x3+x4+x5) * (1.0f/6.0f);
            s_sm += fabsf(x0-m)+fabsf(x1-m)+fabsf(x2-m)
                  + fabsf(x3-m)+fabsf(x4-m)+fabsf(x5-m);
        }
    }

    // ---- block reduction: wave shuffle + 4-wave LDS
    #pragma unroll
    for (int off = 32; off > 0; off >>= 1) {
        s_l1a += __shfl_down(s_l1a, off, 64);
        s_l1b += __shfl_down(s_l1b, off, 64);
        s_sm  += __shfl_down(s_sm,  off, 64);
    }
    __shared__ float red0[4], red1[4], red2[4];
    int wave = tid >> 6, lane = tid & 63;
    if (lane == 0) { red0[wave] = s_l1a; red1[wave] = s_l1b; red2[wave] = s_sm; }
    __syncthreads();

    if (tid == 0) {
        partials[blockIdx.x]          = red0[0] + red0[1] + red0[2] + red0[3];
        partials[nb + blockIdx.x]     = red1[0] + red1[1] + red1[2] + red1[3];
        partials[2 * nb + blockIdx.x] = red2[0] + red2[1] + red2[2] + red2[3];
    }
}

// Stage 2: one 256-thread block reduces nb partial triples (double) + finalizes.
__global__ __launch_bounds__(256) void loss_reduce_kernel(
    const float* __restrict__ partials, int nb,
    float* __restrict__ out, int N, int M)
{
    double a = 0.0, b = 0.0, c = 0.0;
    for (int i = threadIdx.x; i < nb; i += 256) {
        a += (double)partials[i];
        b += (double)partials[nb + i];
        c += (double)partials[2 * nb + i];
    }
    #pragma unroll
    for (int off = 32; off > 0; off >>= 1) {
        a += __shfl_down(a, off, 64);
        b += __shfl_down(b, off, 64);
        c += __shfl_down(c, off, 64);
    }
    __shared__ double ra[4], rb[4], rc[4];
    int wave = threadIdx.x >> 6, lane = threadIdx.x & 63;
    if (lane == 0) { ra[wave] = a; rb[wave] = b; rc[wave] = c; }
    __syncthreads();

    if (threadIdx.x == 0) {
        double sa = ra[0] + ra[1] + ra[2] + ra[3];
        double sb = rb[0] + rb[1] + rb[2] + rb[3];
        double sc = rc[0] + rc[1] + rc[2] + rc[3];
        double l1     = sa / (double)N + sb / (double)M;
        double smooth = sc / (double)CHUNK;
        double total  = l1 + 100.0 * smooth;
        out[0] = (float)total;
        out[1] = (float)l1;
        out[2] = (float)smooth;
    }
}

extern "C" void kernel_launch(void* const* d_in, const int* in_sizes, int n_in,
                              void* d_out, int out_size, void* d_ws, size_t ws_size,
                              hipStream_t stream) {
    const float* resnet = (const float*)d_in[0];
    const float* gru    = (const float*)d_in[1];
    const float* avgp   = (const float*)d_in[2];
    const float* y      = (const float*)d_in[3];
    const float* avgh   = (const float*)d_in[4];
    float* out = (float*)d_out;

    int N = in_sizes[0];          // 3,000,000
    int M = in_sizes[2];          // 500,000
    int C = N / CHUNK;            // 500,000 chunks

    int Cq  = C >> 2;             // 125,000 quads
    int Mv4 = M >> 2;             // 125,000 float4s
    int work = (Cq > Mv4) ? Cq : Mv4;
    if (work < 1) work = 1;
    int nb = (work + BLK - 1) / BLK;          // 489 blocks

    float* partials = (float*)d_ws;           // 3 * nb floats

    loss_partial_kernel<<<nb, BLK, 0, stream>>>(resnet, gru, avgp, y, avgh,
                                                partials, nb, C, M, N);
    loss_reduce_kernel<<<1, 256, 0, stream>>>(partials, nb, out, N, M);
}